// Round 4
// baseline (27133.127 us; speedup 1.0000x reference)
//
#include <hip/hip_runtime.h>
#include <cstdint>
#include <cmath>

// Problem constants
#define B_    8
#define H_    72
#define W_    72
#define C_    16
#define C3_   48
#define HP_   16
#define HE_   128
#define T_    64
#define NCELL 41472      // B*H*W
#define NEDGE 2272       // (2*72 + 2*70) * 8 boundary cells
#define NCG   648        // NCELL/64 cell groups
#define RBLK  72         // ring blocks (8 waves each = 576 ring waves)

// ---------------------------------------------------------------------------
// JAX threefry2x32 (20 rounds)
// ---------------------------------------------------------------------------
__host__ __device__ __forceinline__ void threefry2x32(uint32_t k0, uint32_t k1,
                                                      uint32_t& x0, uint32_t& x1) {
  uint32_t ks2 = k0 ^ k1 ^ 0x1BD11BDAu;
  x0 += k0; x1 += k1;
#define TF_R(r) { x0 += x1; x1 = (x1 << (r)) | (x1 >> (32 - (r))); x1 ^= x0; }
  TF_R(13) TF_R(15) TF_R(26) TF_R(6)
  x0 += k1; x1 += ks2 + 1u;
  TF_R(17) TF_R(29) TF_R(16) TF_R(24)
  x0 += ks2; x1 += k0 + 2u;
  TF_R(13) TF_R(15) TF_R(26) TF_R(6)
  x0 += k0; x1 += k1 + 3u;
  TF_R(17) TF_R(29) TF_R(16) TF_R(24)
  x0 += k1; x1 += ks2 + 4u;
  TF_R(13) TF_R(15) TF_R(26) TF_R(6)
  x0 += ks2; x1 += k0 + 5u;
#undef TF_R
}

// ---------------------------------------------------------------------------
// init: f32 input -> f64 state; un = 1
// ---------------------------------------------------------------------------
__global__ void k_init(const float* __restrict__ xin, double* __restrict__ xA,
                       double* __restrict__ un) {
  int idx = blockIdx.x * 256 + threadIdx.x;
  if (idx < NCELL * C_) xA[idx] = (double)xin[idx];
  if (idx < NCELL) un[idx] = 1.0;
}

// ---------------------------------------------------------------------------
// prep (once): effective 5x5 conv1 weights (conv1 o perceive, exact f64
// combination), f64 copies of fc0 (transposed [e][k]), fc1, w2, w1, biases.
// ---------------------------------------------------------------------------
__global__ void k_prep(const float* __restrict__ w1, const float* __restrict__ b1,
                       const float* __restrict__ f0w, const float* __restrict__ f0b,
                       const float* __restrict__ f1w, const float* __restrict__ w2,
                       double* __restrict__ weffd, double* __restrict__ b1d,
                       double* __restrict__ fc0t, double* __restrict__ fc1d,
                       double* __restrict__ w2d, double* __restrict__ f0bd,
                       double* __restrict__ w1d) {
  int gid = blockIdx.x * 256 + threadIdx.x;
  const int stride = 26 * 256;
  // w_eff[u][v][ic][oc]
  for (int t = gid; t < 6400; t += stride) {
    int oc = t & 15;
    int c  = (t >> 4) & 15;
    int pos = t >> 8;             // 0..24
    int u = pos / 5, v = pos % 5;
    double acc = 0.0;
    for (int ei = 0; ei < 3; ei++) {
      int di = u - ei; if (di < 0 || di > 2) continue;
      for (int ej = 0; ej < 3; ej++) {
        int dj = v - ej; if (dj < 0 || dj > 2) continue;
        const float* wb = w1 + (size_t)((ei * 3 + ej) * C3_) * HP_ + oc;
        if (di == 1 && dj == 1) acc += (double)wb[c * HP_];
        double rf1 = (di == 0) ? -0.125 : (di == 2) ? 0.125 : 0.0;
        if (rf1 != 0.0) {
          double cf1 = (dj == 1) ? 2.0 : 1.0;
          acc += (double)wb[(C_ + c) * HP_] * (rf1 * cf1);
        }
        double cf2 = (dj == 0) ? -0.125 : (dj == 2) ? 0.125 : 0.0;
        if (cf2 != 0.0) {
          double rf2 = (di == 1) ? 2.0 : 1.0;
          acc += (double)wb[(2 * C_ + c) * HP_] * (cf2 * rf2);
        }
      }
    }
    weffd[t] = acc;
  }
  // fc0 transposed: fc0t[e*48 + k] = f0w[k*128 + e]
  for (int t = gid; t < C3_ * HE_; t += stride) {
    int k = t >> 7, e = t & 127;
    fc0t[e * C3_ + k] = (double)f0w[t];
  }
  for (int t = gid; t < HE_ * C_; t += stride) fc1d[t] = (double)f1w[t];
  for (int t = gid; t < 144; t += stride) w2d[t] = (double)w2[t];
  for (int t = gid; t < HE_; t += stride) f0bd[t] = (double)f0b[t];
  for (int t = gid; t < HP_; t += stride) b1d[t] = (double)b1[t];
  for (int t = gid; t < 3 * 3 * C3_ * HP_; t += stride) w1d[t] = (double)w1[t];
}

// ---------------------------------------------------------------------------
// conv1 interior K-chunk: positions [P0,P1) of the 5x5 effective kernel,
// compile-time unrolled so addresses/masks fold and scalar weight loads
// can be batched by the scheduler.
// ---------------------------------------------------------------------------
template <int P0, int P1>
__device__ __forceinline__ void conv1_chunk(const double* __restrict__ x,
    const double* __restrict__ weffd, int i, int j, int b, int ocb,
    double (&acc)[8]) {
#pragma unroll
  for (int p = P0; p < P1; ++p) {
    const int u = p / 5, v = p % 5;
    int ii = i + u - 2, jj = j + v - 2;
    if (ii < 0 || ii >= H_ || jj < 0 || jj >= W_) continue;
    const double* xp = x + ((size_t)((b * H_ + ii) * W_ + jj) << 4);
    const double* wp = weffd + p * 256 + ocb;   // wave-uniform -> s_load
    double xv[16];
#pragma unroll
    for (int ic = 0; ic < 16; ic++) xv[ic] = xp[ic];
#pragma unroll
    for (int ic = 0; ic < 16; ic++) {
#pragma unroll
      for (int o = 0; o < 8; o++)
        acc[o] = fma(xv[ic], wp[ic * 16 + o], acc[o]);
    }
  }
}

// ---------------------------------------------------------------------------
// conv1 fused with perceive. 8 waves per 64-cell group:
//   wave = (oc-half = wv&1, K-quarter = wv>>1). Partial accs reduced in LDS;
//   leader waves (wv 0/1) add bias, relu, store interior cells.
// Ring blocks (>= NCG): exact two-stage math, one wave-uniform oc per wave.
// ---------------------------------------------------------------------------
__global__ void __launch_bounds__(512) k_conv1(const double* __restrict__ x,
    const double* __restrict__ weffd, const double* __restrict__ b1d,
    const double* __restrict__ w1d, double* __restrict__ hbuf) {
  __shared__ double part[8][64][9];   // [wave][cell-lane][8 oc + pad] = 36.9 KB
  int lane = threadIdx.x & 63;
  int wv = __builtin_amdgcn_readfirstlane(threadIdx.x >> 6);   // 0..7
  if (blockIdx.x < NCG) {
    int ocb = (wv & 1) << 3;           // wave-uniform oc base
    int kq  = wv >> 1;                 // wave-uniform K-quarter
    int cell = blockIdx.x * 64 + lane;
    int j = cell % W_; int t2 = cell / W_; int i = t2 % H_; int b = t2 / H_;
    double acc[8];
#pragma unroll
    for (int o = 0; o < 8; o++) acc[o] = 0.0;
    if (kq == 0)      conv1_chunk<0, 7>(x, weffd, i, j, b, ocb, acc);
    else if (kq == 1) conv1_chunk<7, 13>(x, weffd, i, j, b, ocb, acc);
    else if (kq == 2) conv1_chunk<13, 19>(x, weffd, i, j, b, ocb, acc);
    else              conv1_chunk<19, 25>(x, weffd, i, j, b, ocb, acc);
#pragma unroll
    for (int o = 0; o < 8; o++) part[wv][lane][o] = acc[o];
    __syncthreads();
    if (wv < 2) {
      bool interior = (i > 0 && i < H_ - 1 && j > 0 && j < W_ - 1);
      double s[8];
#pragma unroll
      for (int o = 0; o < 8; o++)
        s[o] = b1d[ocb + o] + part[wv][lane][o] + part[wv + 2][lane][o]
             + part[wv + 4][lane][o] + part[wv + 6][lane][o];
      if (interior) {
        double* hp = hbuf + ((size_t)cell << 4) + ocb;
#pragma unroll
        for (int o = 0; o < 8; o++) hp[o] = s[o] > 0.0 ? s[o] : 0.0;
      }
    }
  } else {
    // ---- boundary ring: exact two-stage; one oc per wave (uniform) ----
    int gw = (blockIdx.x - NCG) * 8 + wv;   // 0..575
    int oc = gw & 15;                       // wave-uniform
    int grp = gw >> 4;                      // 0..35
    int ecell = (grp << 6) + lane;
    if (ecell >= NEDGE) return;
    int b = ecell / 284, r = ecell % 284;
    int i, j;
    if (r < 72)       { i = 0;       j = r; }
    else if (r < 144) { i = H_ - 1;  j = r - 72; }
    else if (r < 214) { i = r - 143; j = 0; }
    else              { i = r - 213; j = W_ - 1; }
    int cell = (b * H_ + i) * W_ + j;
    double acc = b1d[oc];
    for (int ei = 0; ei < 3; ei++) {
      int pi = i + ei - 1; if (pi < 0 || pi >= H_) continue;
      for (int ej = 0; ej < 3; ej++) {
        int pj = j + ej - 1; if (pj < 0 || pj >= W_) continue;
        const double* wb = w1d + (size_t)((ei * 3 + ej) * C3_) * HP_ + oc;
        for (int c = 0; c < C_; c++) {
          double v[3][3];
#pragma unroll
          for (int a2 = 0; a2 < 3; a2++) {
#pragma unroll
            for (int b2i = 0; b2i < 3; b2i++) {
              int ii2 = pi + a2 - 1, jj2 = pj + b2i - 1;
              bool ok = (ii2 >= 0 && ii2 < H_ && jj2 >= 0 && jj2 < W_);
              v[a2][b2i] = ok ? x[(((size_t)((b * H_ + ii2) * W_ + jj2)) << 4) + c] : 0.0;
            }
          }
          double ctr = v[1][1];
          double dw1 = (-v[0][0] - 2.0 * v[0][1] - v[0][2] + v[2][0] + 2.0 * v[2][1] + v[2][2]) * 0.125;
          double dw2 = (-v[0][0] + v[0][2] - 2.0 * v[1][0] + 2.0 * v[1][2] - v[2][0] + v[2][2]) * 0.125;
          acc += ctr * wb[c * HP_] + dw1 * wb[(C_ + c) * HP_] + dw2 * wb[(2 * C_ + c) * HP_];
        }
      }
    }
    hbuf[((size_t)cell << 4) + oc] = acc > 0.0 ? acc : 0.0;
  }
}

// ---------------------------------------------------------------------------
// fused conv2 + update. 8 waves per 64-cell group; wave wv owns hidden units
// e in [wv*16, wv*16+16). Every wave recomputes perc on the fly (bit-identical
// formulas). Partial dx reduced through LDS; wave 0 does conv2/lambda/RNG/
// bookkeeping and writes xn.
// ---------------------------------------------------------------------------
__global__ void __launch_bounds__(512) k_upd(
    const double* __restrict__ x, const double* __restrict__ hbuf,
    const double* __restrict__ lamPrev, const double* __restrict__ fc0t,
    const double* __restrict__ fc1d, const double* __restrict__ w2d,
    const double* __restrict__ f0bd, const float* __restrict__ b2,
    double* __restrict__ lamNext, double* __restrict__ xn,
    float* __restrict__ out_upd, double* __restrict__ un,
    float* __restrict__ out_lam, double* __restrict__ p_buf,
    uint32_t k0, uint32_t k1, int n) {
  __shared__ double sdx[7][64][17];   // waves 1..7 partials, padded = 60.9 KB
  int lane = threadIdx.x & 63;
  int wv = __builtin_amdgcn_readfirstlane(threadIdx.x >> 6);  // 0..7
  int cell = (blockIdx.x << 6) + lane;
  int j = cell % W_; int t2 = cell / W_; int i = t2 % H_; int b = t2 / H_;

  // ---- perceive on the fly (all waves; bit-identical formulas) ----
  double pv[C3_];
#pragma unroll
  for (int k = 0; k < C3_; k++) pv[k] = 0.0;
#pragma unroll
  for (int p = 0; p < 9; p++) {
    const int di = p / 3, dj = p % 3;
    const double k1c = (di == 0 ? -0.125 : di == 2 ? 0.125 : 0.0) * (dj == 1 ? 2.0 : 1.0);
    const double k2c = (dj == 0 ? -0.125 : dj == 2 ? 0.125 : 0.0) * (di == 1 ? 2.0 : 1.0);
    int ii = i + di - 1, jj = j + dj - 1;
    if (ii < 0 || ii >= H_ || jj < 0 || jj >= W_) continue;
    const double* xp = x + ((size_t)((b * H_ + ii) * W_ + jj) << 4);
#pragma unroll
    for (int c = 0; c < C_; c++) {
      double xv = xp[c];
      if (p == 4) pv[c] += xv;
      if (k1c != 0.0) pv[C_ + c] = fma(k1c, xv, pv[C_ + c]);
      if (k2c != 0.0) pv[2 * C_ + c] = fma(k2c, xv, pv[2 * C_ + c]);
    }
  }

  // ---- MLP layers for this wave's 16-e slice; scalar weights ----
  double dx[C_];
#pragma unroll
  for (int c = 0; c < C_; c++) dx[c] = 0.0;
  int ebase = wv << 4;   // uniform
#pragma unroll 1
  for (int eg = 0; eg < 16; eg += 4) {
    const double* wrow = fc0t + (size_t)(ebase + eg) * C3_;   // uniform
    double a0 = f0bd[ebase + eg + 0];
    double a1 = f0bd[ebase + eg + 1];
    double a2 = f0bd[ebase + eg + 2];
    double a3 = f0bd[ebase + eg + 3];
#pragma unroll
    for (int k = 0; k < C3_; k++) {
      a0 = fma(pv[k], wrow[k], a0);
      a1 = fma(pv[k], wrow[C3_ + k], a1);
      a2 = fma(pv[k], wrow[2 * C3_ + k], a2);
      a3 = fma(pv[k], wrow[3 * C3_ + k], a3);
    }
    a0 = a0 > 0.0 ? a0 : 0.0;
    a1 = a1 > 0.0 ? a1 : 0.0;
    a2 = a2 > 0.0 ? a2 : 0.0;
    a3 = a3 > 0.0 ? a3 : 0.0;
    const double* v0 = fc1d + ((size_t)(ebase + eg) << 4);    // uniform
#pragma unroll
    for (int c = 0; c < C_; c++) {
      double s = fma(a0, v0[c], dx[c]);
      s = fma(a1, v0[16 + c], s);
      s = fma(a2, v0[32 + c], s);
      s = fma(a3, v0[48 + c], s);
      dx[c] = s;
    }
  }

  if (wv != 0) {
#pragma unroll
    for (int c = 0; c < C_; c++) sdx[wv - 1][lane][c] = dx[c];
  }
  __syncthreads();
  if (wv != 0) return;

#pragma unroll 1
  for (int w = 0; w < 7; w++) {
#pragma unroll
    for (int c = 0; c < C_; c++) dx[c] += sdx[w][lane][c];
  }

  // ---- conv2 -> fresh lambda (wave 0 only) ----
  double z = (double)b2[0];
  for (int di = 0; di < 3; di++) {
    int ii = i + di - 1; if (ii < 0 || ii >= H_) continue;
    for (int dj = 0; dj < 3; dj++) {
      int jj = j + dj - 1; if (jj < 0 || jj >= W_) continue;
      const double* hh = hbuf + ((size_t)((b * H_ + ii) * W_ + jj) << 4);
      const double* ww = w2d + (di * 3 + dj) * HP_;   // uniform
#pragma unroll
      for (int ic = 0; ic < HP_; ic++) z = fma(hh[ic], ww[ic], z);
    }
  }
  double lamF = 1.0 / (1.0 + exp(-z));
  lamNext[cell] = lamF;
  double l = (n == 0) ? lamF : lamPrev[cell];

  // ---- scan bookkeeping with lagged lam ----
  if (n >= 1) {
    size_t o = (size_t)(n - 1) * NCELL + cell;
    out_lam[o] = (float)l;
    double u = un[cell];
    p_buf[o] = u * l + 1e-6;
    un[cell] = u * (1.0 - l);
  }

  // ---- RNG + state write ----
  uint32_t r0 = 0u, r1 = (uint32_t)cell;
  threefry2x32(k0, k1, r0, r1);
  double uf = (double)(r0 ^ r1) * 0x1p-32;
  double upd = (uf < l) ? 0.0 : 1.0;
  out_upd[(size_t)n * NCELL + cell] = (float)upd;
  const double* xc = x + ((size_t)cell << 4);
  double* xo = xn + ((size_t)cell << 4);
#pragma unroll
  for (int c = 0; c < C_; c++) xo[c] = xc[c] + dx[c] * upd;
}

// ---------------------------------------------------------------------------
// life mask: x_new = xn * (alive(x_old) & alive(xn)); emit x_steps[n]
// thread = (cell, c)
// ---------------------------------------------------------------------------
__global__ void k_life(const double* __restrict__ xold, const double* __restrict__ xn,
                       double* __restrict__ xout, float* __restrict__ out_x, int n) {
  int idx = blockIdx.x * 256 + threadIdx.x;
  int c = idx & 15;
  int cell = idx >> 4;
  int j = cell % W_; int t = cell / W_; int i = t % H_; int b = t / H_;
  double mo = -1e300, mn2 = -1e300;
  for (int di = -1; di <= 1; di++) {
    int ii = i + di; if (ii < 0 || ii >= H_) continue;
    for (int dj = -1; dj <= 1; dj++) {
      int jj = j + dj; if (jj < 0 || jj >= W_) continue;
      size_t nb = (size_t)((b * H_ + ii) * W_ + jj) * C_;
      double a0 = xold[nb + 3]; if (a0 > mo) mo = a0;
      double a1 = xn[nb + 3];   if (a1 > mn2) mn2 = a1;
    }
  }
  bool life = (mo > 0.1) && (mn2 > 0.1);
  double v = life ? xn[((size_t)cell << 4) + c] : 0.0;
  xout[((size_t)cell << 4) + c] = v;
  out_x[(size_t)n * NCELL * C_ + ((size_t)cell << 4) + c] = (float)v;
}

// ---------------------------------------------------------------------------
// final emission for scan step 64
// ---------------------------------------------------------------------------
__global__ void k_emit(const double* __restrict__ lam, const double* __restrict__ un,
                       float* __restrict__ out_lam, double* __restrict__ p_buf) {
  int cell = blockIdx.x * 256 + threadIdx.x;
  double l = lam[cell];
  size_t o = (size_t)(T_ - 1) * NCELL + cell;
  out_lam[o] = (float)l;
  p_buf[o] = un[cell] * l + 1e-6;
}

// ---------------------------------------------------------------------------
// final: p_norm[t] = p[t] / sum_t p[t]
// ---------------------------------------------------------------------------
__global__ void k_pnorm(const double* __restrict__ p_buf, float* __restrict__ out_p) {
  int cell = blockIdx.x * 256 + threadIdx.x;
  double s = 0.0;
  for (int t = 0; t < T_; t++) s += p_buf[(size_t)t * NCELL + cell];
  for (int t = 0; t < T_; t++)
    out_p[(size_t)t * NCELL + cell] = (float)(p_buf[(size_t)t * NCELL + cell] / s);
}

// ---------------------------------------------------------------------------
extern "C" void kernel_launch(void* const* d_in, const int* in_sizes, int n_in,
                              void* d_out, int out_size, void* d_ws, size_t ws_size,
                              hipStream_t stream) {
  const float* xin = (const float*)d_in[0];
  const float* w1  = (const float*)d_in[1];
  const float* b1  = (const float*)d_in[2];
  const float* w2  = (const float*)d_in[3];
  const float* b2  = (const float*)d_in[4];
  const float* f0w = (const float*)d_in[5];
  const float* f0b = (const float*)d_in[6];
  const float* f1w = (const float*)d_in[7];

  float* out     = (float*)d_out;
  float* out_x   = out;                                   // (64, NCELL, 16)
  float* out_p   = out_x + (size_t)T_ * NCELL * C_;       // (64, NCELL)
  float* out_lam = out_p + (size_t)T_ * NCELL;            // (64, NCELL)
  float* out_upd = out_lam + (size_t)T_ * NCELL;          // (64, NCELL)

  // workspace layout (all f64)
  double* ws    = (double*)d_ws;
  double* xA    = ws;                                  // NCELL*16
  double* xB    = xA + (size_t)NCELL * C_;             // NCELL*16
  double* xn    = xB + (size_t)NCELL * C_;             // NCELL*16
  double* hbuf  = xn + (size_t)NCELL * C_;             // NCELL*16
  double* lamA  = hbuf + (size_t)NCELL * HP_;          // NCELL
  double* lamB  = lamA + NCELL;                        // NCELL
  double* un    = lamB + NCELL;                        // NCELL
  double* p_buf = un + NCELL;                          // 64*NCELL
  double* weffd = p_buf + (size_t)T_ * NCELL;          // 6400
  double* fc0t  = weffd + 6400;                        // 128*48
  double* fc1d  = fc0t + HE_ * C3_;                    // 2048
  double* w2d   = fc1d + HE_ * C_;                     // 144
  double* f0bd  = w2d + 144;                           // 128
  double* b1d   = f0bd + HE_;                          // 16
  double* w1d   = b1d + HP_;                           // 6912

  k_init<<<2592, 256, 0, stream>>>(xin, xA, un);
  k_prep<<<26, 256, 0, stream>>>(w1, b1, f0w, f0b, f1w, w2,
                                 weffd, b1d, fc0t, fc1d, w2d, f0bd, w1d);

  double* cur = lamA;   // lagged lam entering iteration n
  double* nxt = lamB;

  for (int n = 0; n <= T_ - 1; n++) {
    k_conv1<<<NCG + RBLK, 512, 0, stream>>>(xA, weffd, b1d, w1d, hbuf);
    uint32_t kx0 = 0u, kx1 = (uint32_t)n;
    threefry2x32(0u, 42u, kx0, kx1);
    k_upd<<<NCG, 512, 0, stream>>>(xA, hbuf, cur, fc0t, fc1d, w2d, f0bd, b2,
                                   (n == 0 ? cur : nxt), xn, out_upd, un,
                                   out_lam, p_buf, kx0, kx1, n);
    k_life<<<2592, 256, 0, stream>>>(xA, xn, xB, out_x, n);
    { double* t = xA; xA = xB; xB = t; }
    if (n >= 1) { double* t = cur; cur = nxt; nxt = t; }
  }

  // scan step 64: emit lam_steps[63], p_steps[63] from cur = L(perc(x62))
  k_emit<<<162, 256, 0, stream>>>(cur, un, out_lam, p_buf);
  k_pnorm<<<162, 256, 0, stream>>>(p_buf, out_p);
}

// Round 5
// 15488.664 us; speedup vs baseline: 1.7518x; 1.7518x over previous
//
#include <hip/hip_runtime.h>
#include <cstdint>
#include <cmath>

// Problem constants
#define B_    8
#define H_    72
#define W_    72
#define C_    16
#define C3_   48
#define HP_   16
#define HE_   128
#define T_    64
#define NCELL 41472      // B*H*W

typedef __attribute__((ext_vector_type(2))) double d2;

// ---------------------------------------------------------------------------
// JAX threefry2x32 (20 rounds)
// ---------------------------------------------------------------------------
__host__ __device__ __forceinline__ void threefry2x32(uint32_t k0, uint32_t k1,
                                                      uint32_t& x0, uint32_t& x1) {
  uint32_t ks2 = k0 ^ k1 ^ 0x1BD11BDAu;
  x0 += k0; x1 += k1;
#define TF_R(r) { x0 += x1; x1 = (x1 << (r)) | (x1 >> (32 - (r))); x1 ^= x0; }
  TF_R(13) TF_R(15) TF_R(26) TF_R(6)
  x0 += k1; x1 += ks2 + 1u;
  TF_R(17) TF_R(29) TF_R(16) TF_R(24)
  x0 += ks2; x1 += k0 + 2u;
  TF_R(13) TF_R(15) TF_R(26) TF_R(6)
  x0 += k0; x1 += k1 + 3u;
  TF_R(17) TF_R(29) TF_R(16) TF_R(24)
  x0 += k1; x1 += ks2 + 4u;
  TF_R(13) TF_R(15) TF_R(26) TF_R(6)
  x0 += ks2; x1 += k0 + 5u;
#undef TF_R
}

// ---------------------------------------------------------------------------
// init: f32 input -> f64 state; un = 1
// ---------------------------------------------------------------------------
__global__ void k_init(const float* __restrict__ xin, double* __restrict__ xA,
                       double* __restrict__ un) {
  int idx = blockIdx.x * 256 + threadIdx.x;
  if (idx < NCELL * C_) xA[idx] = (double)xin[idx];
  if (idx < NCELL) un[idx] = 1.0;
}

// ---------------------------------------------------------------------------
// prep (once): effective 5x5 conv1 weights (conv1 o perceive, exact f64
// combination) + transposed f32 fc0 ([e][k], exact copy).
// ---------------------------------------------------------------------------
__global__ void k_prep(const float* __restrict__ w1, const float* __restrict__ f0w,
                       double* __restrict__ weffd, float* __restrict__ fc0tf) {
  int gid = blockIdx.x * 256 + threadIdx.x;
  const int stride = 26 * 256;
  // w_eff[u][v][ic][oc]
  for (int t = gid; t < 6400; t += stride) {
    int oc = t & 15;
    int c  = (t >> 4) & 15;
    int pos = t >> 8;             // 0..24
    int u = pos / 5, v = pos % 5;
    double acc = 0.0;
    for (int ei = 0; ei < 3; ei++) {
      int di = u - ei; if (di < 0 || di > 2) continue;
      for (int ej = 0; ej < 3; ej++) {
        int dj = v - ej; if (dj < 0 || dj > 2) continue;
        const float* wb = w1 + (size_t)((ei * 3 + ej) * C3_) * HP_ + oc;
        if (di == 1 && dj == 1) acc += (double)wb[c * HP_];
        double rf1 = (di == 0) ? -0.125 : (di == 2) ? 0.125 : 0.0;
        if (rf1 != 0.0) {
          double cf1 = (dj == 1) ? 2.0 : 1.0;
          acc += (double)wb[(C_ + c) * HP_] * (rf1 * cf1);
        }
        double cf2 = (dj == 0) ? -0.125 : (dj == 2) ? 0.125 : 0.0;
        if (cf2 != 0.0) {
          double rf2 = (di == 1) ? 2.0 : 1.0;
          acc += (double)wb[(2 * C_ + c) * HP_] * (cf2 * rf2);
        }
      }
    }
    weffd[t] = acc;
  }
  // fc0 transposed: fc0tf[e*48 + k] = f0w[k*128 + e]  (f32, exact)
  for (int t = gid; t < C3_ * HE_; t += stride) {
    int k = t >> 7, e = t & 127;
    fc0tf[e * C3_ + k] = f0w[t];
  }
}

// ---------------------------------------------------------------------------
// conv1 fused with perceive. thread = (cell, oc); 512 thr = 32 cells x 16 oc.
// w_eff (f64) in LDS, read as 16-address broadcast (conflict-free).
// Interior: 5x5 w_eff on zero-padded x (clamped addr + masked-zero value).
// Ring cells: exact two-stage path per thread, f32 weights from global.
// Grid: 1296 blocks.
// ---------------------------------------------------------------------------
__global__ void __launch_bounds__(512) k_conv1(const double* __restrict__ x,
    const double* __restrict__ weffd, const float* __restrict__ w1f,
    const float* __restrict__ b1f, double* __restrict__ hbuf) {
  __shared__ double sw[6400];   // [pos][ic][oc]  51.2 KB
  for (int t = threadIdx.x; t < 6400; t += 512) sw[t] = weffd[t];
  __syncthreads();
  int oc = threadIdx.x & 15;
  int cs = threadIdx.x >> 4;          // 0..31
  int cell = blockIdx.x * 32 + cs;
  int j = cell % W_; int t2 = cell / W_; int i = t2 % H_; int b = t2 / H_;
  bool ring = (i == 0 || i == H_ - 1 || j == 0 || j == W_ - 1);
  double acc = (double)b1f[oc];
  if (!ring) {
#pragma unroll
    for (int p = 0; p < 25; p++) {
      const int u = p / 5, v = p % 5;
      int ii = i + u - 2, jj = j + v - 2;
      bool ok = ((unsigned)ii < (unsigned)H_) && ((unsigned)jj < (unsigned)W_);
      int iic = ok ? ii : 0;
      int jjc = ok ? jj : 0;
      const double* xp = x + (((size_t)((b * H_ + iic) * W_ + jjc)) << 4);
      const double* wp = sw + p * 256 + oc;
#pragma unroll
      for (int g = 0; g < 8; g++) {
        d2 xv = *(const d2*)(xp + 2 * g);
        double x0 = ok ? xv.x : 0.0;
        double x1 = ok ? xv.y : 0.0;
        acc = fma(x0, wp[(2 * g) * 16], acc);
        acc = fma(x1, wp[(2 * g + 1) * 16], acc);
      }
    }
  } else {
    // ---- boundary ring: exact two-stage (perc zero-pad semantics) ----
    for (int ei = 0; ei < 3; ei++) {
      int pi = i + ei - 1; if (pi < 0 || pi >= H_) continue;
      for (int ej = 0; ej < 3; ej++) {
        int pj = j + ej - 1; if (pj < 0 || pj >= W_) continue;
        const float* wb = w1f + (size_t)((ei * 3 + ej) * C3_) * HP_ + oc;
        for (int c = 0; c < C_; c++) {
          double v[3][3];
#pragma unroll
          for (int a2 = 0; a2 < 3; a2++) {
#pragma unroll
            for (int b2i = 0; b2i < 3; b2i++) {
              int ii2 = pi + a2 - 1, jj2 = pj + b2i - 1;
              bool ok = (ii2 >= 0 && ii2 < H_ && jj2 >= 0 && jj2 < W_);
              v[a2][b2i] = ok ? x[(((size_t)((b * H_ + ii2) * W_ + jj2)) << 4) + c] : 0.0;
            }
          }
          double ctr = v[1][1];
          double dw1 = (-v[0][0] - 2.0 * v[0][1] - v[0][2] + v[2][0] + 2.0 * v[2][1] + v[2][2]) * 0.125;
          double dw2 = (-v[0][0] + v[0][2] - 2.0 * v[1][0] + 2.0 * v[1][2] - v[2][0] + v[2][2]) * 0.125;
          acc += ctr * (double)wb[c * HP_] + dw1 * (double)wb[(C_ + c) * HP_] + dw2 * (double)wb[(2 * C_ + c) * HP_];
        }
      }
    }
  }
  hbuf[((size_t)cell << 4) + oc] = acc > 0.0 ? acc : 0.0;
}

// ---------------------------------------------------------------------------
// fused conv2 + update. 256 thr = 64 cells (lane) x 4 waves.
//  - stage f32 weights to LDS (exact f32->f64 cvt on use)
//  - cooperative perceive: wave wv computes channels 4wv..4wv+3 -> pv LDS
//  - each wave: pv->regs, conv2 ic-slice partial, MLP e-slice 32 -> dx partial
//  - reduce partials through the (dead) pv buffer; wave 0 does lambda/RNG/
//    bookkeeping/xn (verbatim).
// ---------------------------------------------------------------------------
__global__ void __launch_bounds__(256) k_upd(
    const double* __restrict__ x, const double* __restrict__ hbuf,
    const double* __restrict__ lamPrev, const float* __restrict__ fc0tf,
    const float* __restrict__ f1w, const float* __restrict__ w2f,
    const float* __restrict__ f0b, const float* __restrict__ b2,
    double* __restrict__ lamNext, double* __restrict__ xn,
    float* __restrict__ out_upd, double* __restrict__ un,
    float* __restrict__ out_lam, double* __restrict__ p_buf,
    uint32_t k0, uint32_t k1, int n) {
  __shared__ float s0f[HE_ * C3_];   // 24576 B  [e][k]
  __shared__ float s1f[HE_ * C_];    // 8192 B   [e][c]
  __shared__ float sw2[144];
  __shared__ float sb0[HE_];
  __shared__ double upool[3264];     // 26112 B: pv view [64][51] / reduce [3][64][17]
  int tid = threadIdx.x;
  for (int t = tid; t < HE_ * C3_; t += 256) s0f[t] = fc0tf[t];
  for (int t = tid; t < HE_ * C_; t += 256) s1f[t] = f1w[t];
  if (tid < 144) sw2[tid] = w2f[tid];
  if (tid < HE_) sb0[tid] = f0b[tid];

  int lane = tid & 63;
  int wv = __builtin_amdgcn_readfirstlane(tid >> 6);  // 0..3
  int c0 = wv * 4;                                    // uniform channel base
  int cell = (blockIdx.x << 6) + lane;
  int j = cell % W_; int t2 = cell / W_; int i = t2 % H_; int b = t2 / H_;

  // ---- cooperative perceive: this wave's 4 channels (same op order as before)
  double pvx0 = 0.0, pvx1 = 0.0, pvx2 = 0.0, pvx3 = 0.0;
  double pw10 = 0.0, pw11 = 0.0, pw12 = 0.0, pw13 = 0.0;
  double pw20 = 0.0, pw21 = 0.0, pw22 = 0.0, pw23 = 0.0;
#pragma unroll
  for (int p = 0; p < 9; p++) {
    const int di = p / 3, dj = p % 3;
    const double k1c = (di == 0 ? -0.125 : di == 2 ? 0.125 : 0.0) * (dj == 1 ? 2.0 : 1.0);
    const double k2c = (dj == 0 ? -0.125 : dj == 2 ? 0.125 : 0.0) * (di == 1 ? 2.0 : 1.0);
    int ii = i + di - 1, jj = j + dj - 1;
    bool ok = ((unsigned)ii < (unsigned)H_) && ((unsigned)jj < (unsigned)W_);
    int iic = ok ? ii : 0;
    int jjc = ok ? jj : 0;
    const double* xp = x + (((size_t)((b * H_ + iic) * W_ + jjc)) << 4) + c0;
    d2 xa = *(const d2*)xp;
    d2 xb = *(const d2*)(xp + 2);
    double xv0 = ok ? xa.x : 0.0;
    double xv1 = ok ? xa.y : 0.0;
    double xv2 = ok ? xb.x : 0.0;
    double xv3 = ok ? xb.y : 0.0;
    if (p == 4) { pvx0 += xv0; pvx1 += xv1; pvx2 += xv2; pvx3 += xv3; }
    if (k1c != 0.0) {
      pw10 = fma(k1c, xv0, pw10); pw11 = fma(k1c, xv1, pw11);
      pw12 = fma(k1c, xv2, pw12); pw13 = fma(k1c, xv3, pw13);
    }
    if (k2c != 0.0) {
      pw20 = fma(k2c, xv0, pw20); pw21 = fma(k2c, xv1, pw21);
      pw22 = fma(k2c, xv2, pw22); pw23 = fma(k2c, xv3, pw23);
    }
  }
  {
    double* pr = upool + lane * 51;
    pr[c0 + 0] = pvx0; pr[c0 + 1] = pvx1; pr[c0 + 2] = pvx2; pr[c0 + 3] = pvx3;
    pr[16 + c0 + 0] = pw10; pr[16 + c0 + 1] = pw11; pr[16 + c0 + 2] = pw12; pr[16 + c0 + 3] = pw13;
    pr[32 + c0 + 0] = pw20; pr[32 + c0 + 1] = pw21; pr[32 + c0 + 2] = pw22; pr[32 + c0 + 3] = pw23;
  }
  __syncthreads();   // weights staged + pv complete

  // ---- conv2 partial over ic slice [c0, c0+4) (guard structure verbatim) ----
  double z = (wv == 0) ? (double)b2[0] : 0.0;
  for (int di = 0; di < 3; di++) {
    int ii = i + di - 1; if (ii < 0 || ii >= H_) continue;
    for (int dj = 0; dj < 3; dj++) {
      int jj = j + dj - 1; if (jj < 0 || jj >= W_) continue;
      const double* hh = hbuf + (((size_t)((b * H_ + ii) * W_ + jj)) << 4) + c0;
      const float* ww = sw2 + (di * 3 + dj) * HP_ + c0;
      d2 h0 = *(const d2*)hh;
      d2 h1 = *(const d2*)(hh + 2);
      z = fma(h0.x, (double)ww[0], z);
      z = fma(h0.y, (double)ww[1], z);
      z = fma(h1.x, (double)ww[2], z);
      z = fma(h1.y, (double)ww[3], z);
    }
  }

  // ---- pv -> registers (once) ----
  double pv[C3_];
#pragma unroll
  for (int k = 0; k < C3_; k++) pv[k] = upool[lane * 51 + k];

  // ---- MLP for e-slice [wv*32, wv*32+32); f32 weights cvt'd (exact) ----
  double dx[C_];
#pragma unroll
  for (int c = 0; c < C_; c++) dx[c] = 0.0;
  int ebase = wv << 5;   // uniform
#pragma unroll 1
  for (int eg = 0; eg < 32; eg += 4) {
    int e = ebase + eg;
    const float* w0 = s0f + e * C3_;    // uniform address -> LDS broadcast
    double a0 = (double)sb0[e + 0];
    double a1 = (double)sb0[e + 1];
    double a2 = (double)sb0[e + 2];
    double a3 = (double)sb0[e + 3];
#pragma unroll
    for (int k = 0; k < C3_; k++) {
      a0 = fma(pv[k], (double)w0[k], a0);
      a1 = fma(pv[k], (double)w0[C3_ + k], a1);
      a2 = fma(pv[k], (double)w0[2 * C3_ + k], a2);
      a3 = fma(pv[k], (double)w0[3 * C3_ + k], a3);
    }
    a0 = a0 > 0.0 ? a0 : 0.0;
    a1 = a1 > 0.0 ? a1 : 0.0;
    a2 = a2 > 0.0 ? a2 : 0.0;
    a3 = a3 > 0.0 ? a3 : 0.0;
    const float* v0 = s1f + (e << 4);   // uniform
#pragma unroll
    for (int c = 0; c < C_; c++) {
      double s = fma(a0, (double)v0[c], dx[c]);
      s = fma(a1, (double)v0[16 + c], s);
      s = fma(a2, (double)v0[32 + c], s);
      s = fma(a3, (double)v0[48 + c], s);
      dx[c] = s;
    }
  }

  __syncthreads();   // all pv reads done; upool reusable as reduce buffer
  if (wv != 0) {
    double* pr = upool + (wv - 1) * 1088 + lane * 17;
#pragma unroll
    for (int c = 0; c < C_; c++) pr[c] = dx[c];
    pr[16] = z;
  }
  __syncthreads();
  if (wv != 0) return;

  // ---- wave 0: combine partials (ascending wave order) ----
#pragma unroll
  for (int w = 0; w < 3; w++) {
    const double* pr = upool + w * 1088 + lane * 17;
#pragma unroll
    for (int c = 0; c < C_; c++) dx[c] += pr[c];
    z += pr[16];
  }

  double lamF = 1.0 / (1.0 + exp(-z));
  lamNext[cell] = lamF;
  double l = (n == 0) ? lamF : lamPrev[cell];

  // ---- scan bookkeeping with lagged lam ----
  if (n >= 1) {
    size_t o = (size_t)(n - 1) * NCELL + cell;
    out_lam[o] = (float)l;
    double u = un[cell];
    p_buf[o] = u * l + 1e-6;
    un[cell] = u * (1.0 - l);
  }

  // ---- RNG + state write ----
  uint32_t r0 = 0u, r1 = (uint32_t)cell;
  threefry2x32(k0, k1, r0, r1);
  double uf = (double)(r0 ^ r1) * 0x1p-32;
  double upd = (uf < l) ? 0.0 : 1.0;
  out_upd[(size_t)n * NCELL + cell] = (float)upd;
  const double* xc = x + ((size_t)cell << 4);
  double* xo = xn + ((size_t)cell << 4);
#pragma unroll
  for (int c = 0; c < C_; c++) xo[c] = xc[c] + dx[c] * upd;
}

// ---------------------------------------------------------------------------
// life mask: x_new = xn * (alive(x_old) & alive(xn)); emit x_steps[n]
// thread = (cell, c)
// ---------------------------------------------------------------------------
__global__ void k_life(const double* __restrict__ xold, const double* __restrict__ xn,
                       double* __restrict__ xout, float* __restrict__ out_x, int n) {
  int idx = blockIdx.x * 256 + threadIdx.x;
  int c = idx & 15;
  int cell = idx >> 4;
  int j = cell % W_; int t = cell / W_; int i = t % H_; int b = t / H_;
  double mo = -1e300, mn2 = -1e300;
  for (int di = -1; di <= 1; di++) {
    int ii = i + di; if (ii < 0 || ii >= H_) continue;
    for (int dj = -1; dj <= 1; dj++) {
      int jj = j + dj; if (jj < 0 || jj >= W_) continue;
      size_t nb = (size_t)((b * H_ + ii) * W_ + jj) * C_;
      double a0 = xold[nb + 3]; if (a0 > mo) mo = a0;
      double a1 = xn[nb + 3];   if (a1 > mn2) mn2 = a1;
    }
  }
  bool life = (mo > 0.1) && (mn2 > 0.1);
  double v = life ? xn[((size_t)cell << 4) + c] : 0.0;
  xout[((size_t)cell << 4) + c] = v;
  out_x[(size_t)n * NCELL * C_ + ((size_t)cell << 4) + c] = (float)v;
}

// ---------------------------------------------------------------------------
// final emission for scan step 64
// ---------------------------------------------------------------------------
__global__ void k_emit(const double* __restrict__ lam, const double* __restrict__ un,
                       float* __restrict__ out_lam, double* __restrict__ p_buf) {
  int cell = blockIdx.x * 256 + threadIdx.x;
  double l = lam[cell];
  size_t o = (size_t)(T_ - 1) * NCELL + cell;
  out_lam[o] = (float)l;
  p_buf[o] = un[cell] * l + 1e-6;
}

// ---------------------------------------------------------------------------
// final: p_norm[t] = p[t] / sum_t p[t]
// ---------------------------------------------------------------------------
__global__ void k_pnorm(const double* __restrict__ p_buf, float* __restrict__ out_p) {
  int cell = blockIdx.x * 256 + threadIdx.x;
  double s = 0.0;
  for (int t = 0; t < T_; t++) s += p_buf[(size_t)t * NCELL + cell];
  for (int t = 0; t < T_; t++)
    out_p[(size_t)t * NCELL + cell] = (float)(p_buf[(size_t)t * NCELL + cell] / s);
}

// ---------------------------------------------------------------------------
extern "C" void kernel_launch(void* const* d_in, const int* in_sizes, int n_in,
                              void* d_out, int out_size, void* d_ws, size_t ws_size,
                              hipStream_t stream) {
  const float* xin = (const float*)d_in[0];
  const float* w1  = (const float*)d_in[1];
  const float* b1  = (const float*)d_in[2];
  const float* w2  = (const float*)d_in[3];
  const float* b2  = (const float*)d_in[4];
  const float* f0w = (const float*)d_in[5];
  const float* f0b = (const float*)d_in[6];
  const float* f1w = (const float*)d_in[7];

  float* out     = (float*)d_out;
  float* out_x   = out;                                   // (64, NCELL, 16)
  float* out_p   = out_x + (size_t)T_ * NCELL * C_;       // (64, NCELL)
  float* out_lam = out_p + (size_t)T_ * NCELL;            // (64, NCELL)
  float* out_upd = out_lam + (size_t)T_ * NCELL;          // (64, NCELL)

  // workspace layout
  double* ws    = (double*)d_ws;
  double* xA    = ws;                                  // NCELL*16
  double* xB    = xA + (size_t)NCELL * C_;             // NCELL*16
  double* xn    = xB + (size_t)NCELL * C_;             // NCELL*16
  double* hbuf  = xn + (size_t)NCELL * C_;             // NCELL*16
  double* lamA  = hbuf + (size_t)NCELL * HP_;          // NCELL
  double* lamB  = lamA + NCELL;                        // NCELL
  double* un    = lamB + NCELL;                        // NCELL
  double* p_buf = un + NCELL;                          // 64*NCELL
  double* weffd = p_buf + (size_t)T_ * NCELL;          // 6400 f64
  float*  fc0tf = (float*)(weffd + 6400);              // 6144 f32

  k_init<<<2592, 256, 0, stream>>>(xin, xA, un);
  k_prep<<<26, 256, 0, stream>>>(w1, f0w, weffd, fc0tf);

  double* cur = lamA;   // lagged lam entering iteration n
  double* nxt = lamB;

  for (int n = 0; n <= T_ - 1; n++) {
    k_conv1<<<1296, 512, 0, stream>>>(xA, weffd, w1, b1, hbuf);
    uint32_t kx0 = 0u, kx1 = (uint32_t)n;
    threefry2x32(0u, 42u, kx0, kx1);
    k_upd<<<648, 256, 0, stream>>>(xA, hbuf, cur, fc0tf, f1w, w2, f0b, b2,
                                   (n == 0 ? cur : nxt), xn, out_upd, un,
                                   out_lam, p_buf, kx0, kx1, n);
    k_life<<<2592, 256, 0, stream>>>(xA, xn, xB, out_x, n);
    { double* t = xA; xA = xB; xB = t; }
    if (n >= 1) { double* t = cur; cur = nxt; nxt = t; }
  }

  // scan step 64: emit lam_steps[63], p_steps[63] from cur = L(perc(x62))
  k_emit<<<162, 256, 0, stream>>>(cur, un, out_lam, p_buf);
  k_pnorm<<<162, 256, 0, stream>>>(p_buf, out_p);
}